// Round 21
// baseline (168.924 us; speedup 1.0000x reference)
//
#include <hip/hip_runtime.h>
#include <hip/hip_bf16.h>

#define S_LEN 2048
#define IN_D  256
#define NHEAD 16
#define HDIM  16

typedef short s8v __attribute__((ext_vector_type(8)));
typedef float f4v __attribute__((ext_vector_type(4)));
typedef float f16v __attribute__((ext_vector_type(16)));

__device__ __forceinline__ ushort f2b(float f) {
    union { float f; unsigned u; } x; x.f = f;
    unsigned r = x.u + 0x7fffu + ((x.u >> 16) & 1u);   // RNE, inputs finite
    return (ushort)(r >> 16);
}

// ---- fragment-order layouts (all attn loads wave-contiguous) ----
// qh [bh][qb(64)][hi(2)][l31(32)][j(8)]  (pre-scaled by 0.25*log2e)
// kh [bh][t (64)][hi(2)][l31(32)][j(8)]
// vt [bh][t (64)][half(2)][hi(2)][d(16)][j(8)]

// -------- projection: 128x128 tile, 16 waves, X+W LDS with XOR chunk swizzle --------
// (byte-identical to R18/R20) conflict-free ds_read_b128; staging fully coalesced.
__global__ __launch_bounds__(1024, 4) void proj_kernel(
    const float* __restrict__ Q, const float* __restrict__ K, const float* __restrict__ V,
    const float* __restrict__ WQ, const float* __restrict__ WK, const float* __restrict__ WV,
    ushort* __restrict__ qh, ushort* __restrict__ kh, ushort* __restrict__ vt)
{
    __shared__ ushort xl[128 * 256];              // 64 KB
    __shared__ ushort wl[128 * 256];              // 64 KB
    const int which = blockIdx.y;
    const float* X = (which == 0) ? Q : (which == 1) ? K : V;
    const float* W = (which == 0) ? WQ : (which == 1) ? WK : WV;

    const int tid = threadIdx.x;
    const int wv = tid >> 6, lane = tid & 63;
    const int l31 = lane & 31, hi = lane >> 5;
    const int rg = blockIdx.x >> 1;               // 32 row-groups of 128
    const int cg = blockIdx.x & 1;                // 2 col-groups of 128
    const int n0 = cg * 128;

    {
        const float* xs = X + (size_t)rg * 128 * IN_D;
        const int ch = tid & 31;                  // chunk 0..31 (k-offset ch*8)
#pragma unroll
        for (int it = 0; it < 4; ++it) {
            const int row = (tid >> 5) + 32 * it;
            const float* xp = xs + (size_t)row * IN_D + ch * 8;
            const f4v x0 = *(const f4v*)xp;
            const f4v x1 = *(const f4v*)(xp + 4);
            union { unsigned u[4]; s8v v; } au;
            asm("v_cvt_pk_bf16_f32 %0, %1, %2" : "=v"(au.u[0]) : "v"(x0[0]), "v"(x0[1]));
            asm("v_cvt_pk_bf16_f32 %0, %1, %2" : "=v"(au.u[1]) : "v"(x0[2]), "v"(x0[3]));
            asm("v_cvt_pk_bf16_f32 %0, %1, %2" : "=v"(au.u[2]) : "v"(x1[0]), "v"(x1[1]));
            asm("v_cvt_pk_bf16_f32 %0, %1, %2" : "=v"(au.u[3]) : "v"(x1[2]), "v"(x1[3]));
            *(s8v*)&xl[row * 256 + ((ch ^ (row & 31)) * 8)] = au.v;
        }
    }
    {
        const int c4 = (tid & 31) * 4;            // col 0,4,..,124
#pragma unroll
        for (int it = 0; it < 8; ++it) {
            const int k = (tid >> 5) * 8 + it;    // 0..255
            const f4v w4 = *(const f4v*)(W + (size_t)k * (NHEAD * HDIM) + n0 + c4);
#pragma unroll
            for (int j = 0; j < 4; ++j) {
                const int col = c4 + j;
                wl[col * 256 + ((k >> 3) ^ (col & 31)) * 8 + (k & 7)] = f2b(w4[j]);
            }
        }
    }
    __syncthreads();

    const int rt2 = wv >> 2, ct2 = wv & 3;        // 4x4 sub-tiles of 32x32

    f16v acc = {};
#pragma unroll 4
    for (int ks = 0; ks < 16; ++ks) {
        const int pos = (2 * ks + hi) ^ l31;      // row&31 == l31 for both operands
        const s8v a = *(const s8v*)&xl[(rt2 * 32 + l31) * 256 + pos * 8];
        const s8v b = *(const s8v*)&wl[(ct2 * 32 + l31) * 256 + pos * 8];
        acc = __builtin_amdgcn_mfma_f32_32x32x16_bf16(a, b, acc, 0, 0, 0);
    }

    const int rt  = rg * 4 + rt2;
    const int qbt = rt & 63;
    const int bI  = rt >> 6;
    const int n = n0 + ct2 * 32 + l31;
    const int h = n >> 4, d = n & 15;
    const int bh = bI * NHEAD + h;
    if (which == 2) {
        ushort* vb = vt + (size_t)bh * 32768 + qbt * 512 + d * 8 + 4 * hi;
#pragma unroll
        for (int g2 = 0; g2 < 4; ++g2) {          // regs 4g..4g+3 -> j consecutive
            unsigned long long pk = 0;
#pragma unroll
            for (int j = 0; j < 4; ++j)
                pk |= (unsigned long long)f2b(acc[g2 * 4 + j]) << (16 * j);
            *(unsigned long long*)(vb + (g2 >> 1) * 256 + (g2 & 1) * 128) = pk;
        }
    } else {
        ushort* dst = ((which == 0) ? qh : kh) +
                      (size_t)bh * 32768 + qbt * 512 + (d >> 3) * 256 + (d & 7);
        const float scale = (which == 0) ? 0.25f * 1.44269504f : 1.0f;  // 1/sqrt(D)*log2e
#pragma unroll
        for (int r = 0; r < 16; ++r) {
            const int l31s = (r & 3) + 8 * (r >> 2) + 4 * hi;
            dst[l31s * 8] = f2b(acc[r] * scale);
        }
    }
}

// ---- causal attention: R20 body; ONE change: 8 waves/block (512 thr) ----
// 1024 blocks x 8 waves = 8192 waves = 8 waves/SIMD (32 waves/CU, HW max) to hide the
// per-item dependency chain. Items strided over 8 waves. VGPR capped at 64 by
// __launch_bounds__(512,8) -- same count the 4-wave body compiled to (no spill).
// XCD-aware mapping unchanged: bid=(bh&3)*256+qbA*8+(bh>>2).
__global__ __launch_bounds__(512, 8) void attn_kernel(
    const ushort* __restrict__ qh, const ushort* __restrict__ kh,
    const ushort* __restrict__ vt, float* __restrict__ out)
{
    __shared__ float ol[2][8][8][64];             // 32 KB
    __shared__ float ll[2][8][32];                // 2 KB   (34KB <= 40KB @ 4 blocks/CU)
    const int tid = threadIdx.x;
    const int wv = tid >> 6, lane = tid & 63;     // wv = 0..7
    const int l31 = lane & 31, hi = lane >> 5;
    const int bid = blockIdx.x;
    const int bh  = (bid & 7) * 4 + (bid >> 8);   // inverse of the XCD mapping
    const int qbA = (bid >> 3) & 31;              // light stream
    const int qbB = 63 - qbA;                     // heavy stream
    const int ntA = qbA + 1, ntB = qbB + 1;       // ntA + ntB == 65

    const ushort* qp = qh + (size_t)bh * 32768;
    const ushort* kp = kh + (size_t)bh * 32768;
    const ushort* vp = vt + (size_t)bh * 32768;

    const s8v qfA = *(const s8v*)(qp + qbA * 512 + hi * 256 + l31 * 8);
    const s8v qfB = *(const s8v*)(qp + qbB * 512 + hi * 256 + l31 * 8);
    const f16v z16 = {};
    f16v aA0 = {}, aA1 = {}, aB0 = {}, aB1 = {};

    s8v vinit = {};
    if (l31 == 16 || l31 == 20) {
#pragma unroll
        for (int j = 0; j < 8; ++j) vinit[j] = (short)0x3F80;
    }

    auto process = [&](int it) {
        const bool isB = (it < ntB);            // block/wave-uniform
        const int t  = isB ? it : it - ntB;
        const s8v kf = *(const s8v*)(kp + t * 512 + hi * 256 + l31 * 8);
        s8v vf0 = vinit, vf1 = vinit;
        if (l31 < 16) {
            vf0 = *(const s8v*)(vp + t * 512 + hi * 128 + l31 * 8);
            vf1 = *(const s8v*)(vp + t * 512 + 256 + hi * 128 + l31 * 8);
        }
        const s8v qf = isB ? qfB : qfA;
        const int nt = isB ? ntB : ntA;
        const f16v st = __builtin_amdgcn_mfma_f32_32x32x16_bf16(kf, qf, z16, 0, 0, 0);
        float p[16];
#pragma unroll
        for (int r = 0; r < 16; ++r) p[r] = __builtin_amdgcn_exp2f(st[r]);
        if (t == nt - 1) {                      // diagonal tile: zero k > q
#pragma unroll
            for (int r = 0; r < 16; ++r) {
                const int kr = (r & 3) + 8 * (r >> 2) + 4 * hi;
                if (kr > l31) p[r] = 0.f;
            }
        }
        s8v pb[2];
#pragma unroll
        for (int half = 0; half < 2; ++half) {
            unsigned x0, x1, y0, y1;
            asm("v_cvt_pk_bf16_f32 %0, %1, %2" : "=v"(x0) : "v"(p[8*half+0]), "v"(p[8*half+1]));
            asm("v_cvt_pk_bf16_f32 %0, %1, %2" : "=v"(x1) : "v"(p[8*half+2]), "v"(p[8*half+3]));
            asm("v_cvt_pk_bf16_f32 %0, %1, %2" : "=v"(y0) : "v"(p[8*half+4]), "v"(p[8*half+5]));
            asm("v_cvt_pk_bf16_f32 %0, %1, %2" : "=v"(y1) : "v"(p[8*half+6]), "v"(p[8*half+7]));
            auto r0 = __builtin_amdgcn_permlane32_swap(x0, y0, false, false);
            auto r1 = __builtin_amdgcn_permlane32_swap(x1, y1, false, false);
            union { unsigned u[4]; s8v v; } bu;
            bu.u[0] = r0[0]; bu.u[1] = r1[0]; bu.u[2] = r0[1]; bu.u[3] = r1[1];
            pb[half] = bu.v;
        }
        __builtin_amdgcn_s_setprio(1);
        if (isB) {
            aB0 = __builtin_amdgcn_mfma_f32_32x32x16_bf16(vf0, pb[0], aB0, 0, 0, 0);
            aB1 = __builtin_amdgcn_mfma_f32_32x32x16_bf16(vf1, pb[1], aB1, 0, 0, 0);
        } else {
            aA0 = __builtin_amdgcn_mfma_f32_32x32x16_bf16(vf0, pb[0], aA0, 0, 0, 0);
            aA1 = __builtin_amdgcn_mfma_f32_32x32x16_bf16(vf1, pb[1], aA1, 0, 0, 0);
        }
        __builtin_amdgcn_s_setprio(0);
    };

    for (int it0 = 2 * wv; it0 < 65; it0 += 16) {  // 8 waves stride the 65-item list
        process(it0);
        if (it0 + 1 < 65) process(it0 + 1);
    }

#pragma unroll
    for (int j = 0; j < 8; ++j) {
        ol[0][wv][j][lane] = aB0[j] + aB1[j];
        ol[1][wv][j][lane] = aA0[j] + aA1[j];
    }
    if (hi == 0) {
        ll[0][wv][l31] = aB0[8] + aB1[8];
        ll[1][wv][l31] = aA0[8] + aA1[8];
    }
    __syncthreads();

    if (wv < 2) {                               // wave 0 -> stream B, wave 1 -> stream A
        const int ss = wv;
        const int qw = (ss ? qbA : qbB) * 32;
        float l = ((ll[ss][0][l31] + ll[ss][1][l31]) + (ll[ss][2][l31] + ll[ss][3][l31]))
                + ((ll[ss][4][l31] + ll[ss][5][l31]) + (ll[ss][6][l31] + ll[ss][7][l31]));
        const float inv = __builtin_amdgcn_rcpf(l);
        float o[8];
#pragma unroll
        for (int j = 0; j < 8; ++j)
            o[j] = (((ol[ss][0][j][lane] + ol[ss][1][j][lane]) +
                     (ol[ss][2][j][lane] + ol[ss][3][j][lane])) +
                    ((ol[ss][4][j][lane] + ol[ss][5][j][lane]) +
                     (ol[ss][6][j][lane] + ol[ss][7][j][lane]))) * inv;
        const int b = bh >> 4, h = bh & 15;
        f4v o0, o1;
#pragma unroll
        for (int j = 0; j < 4; ++j) { o0[j] = o[j]; o1[j] = o[4 + j]; }
        float* op = out + ((size_t)b * S_LEN + qw + l31) * (NHEAD * HDIM) + h * HDIM;
        *(f4v*)(op + 4 * hi) = o0;        // d = 4*hi + 0..3
        *(f4v*)(op + 8 + 4 * hi) = o1;    // d = 8 + 4*hi + 0..3
    }
}

extern "C" void kernel_launch(void* const* d_in, const int* in_sizes, int n_in,
                              void* d_out, int out_size, void* d_ws, size_t ws_size,
                              hipStream_t stream)
{
    const float* Q  = (const float*)d_in[0];
    const float* K  = (const float*)d_in[1];
    const float* V  = (const float*)d_in[2];
    const float* WQ = (const float*)d_in[3];
    const float* WK = (const float*)d_in[4];
    const float* WV = (const float*)d_in[5];
    float* out = (float*)d_out;

    const size_t mat = (size_t)2 * NHEAD * S_LEN * HDIM;   // 2 MB bf16 each
    ushort* qh = (ushort*)d_ws;
    ushort* kh = qh + mat;
    ushort* vt = kh + mat;

    proj_kernel<<<dim3(64, 3), 1024, 0, stream>>>(Q, K, V, WQ, WK, WV, qh, kh, vt);
    attn_kernel<<<dim3(1024), 512, 0, stream>>>(qh, kh, vt, out);
}

// Round 22
// 126.884 us; speedup vs baseline: 1.3313x; 1.3313x over previous
//
#include <hip/hip_runtime.h>
#include <hip/hip_bf16.h>

#define S_LEN 2048
#define IN_D  256
#define NHEAD 16
#define HDIM  16

typedef short s8v __attribute__((ext_vector_type(8)));
typedef float f4v __attribute__((ext_vector_type(4)));
typedef float f16v __attribute__((ext_vector_type(16)));

__device__ __forceinline__ ushort f2b(float f) {
    union { float f; unsigned u; } x; x.f = f;
    unsigned r = x.u + 0x7fffu + ((x.u >> 16) & 1u);   // RNE, inputs finite
    return (ushort)(r >> 16);
}

// ---- fragment-order layouts (all attn loads wave-contiguous) ----
// qh [bh][qb(64)][hi(2)][l31(32)][j(8)]  (pre-scaled by 0.25*log2e)
// kh [bh][t (64)][hi(2)][l31(32)][j(8)]
// vt [bh][t (64)][half(2)][hi(2)][d(16)][j(8)]

// -------- projection: 128x128 tile, 16 waves, X+W LDS with XOR chunk swizzle --------
// (byte-identical to R18/R20) conflict-free ds_read_b128; staging fully coalesced.
__global__ __launch_bounds__(1024, 4) void proj_kernel(
    const float* __restrict__ Q, const float* __restrict__ K, const float* __restrict__ V,
    const float* __restrict__ WQ, const float* __restrict__ WK, const float* __restrict__ WV,
    ushort* __restrict__ qh, ushort* __restrict__ kh, ushort* __restrict__ vt)
{
    __shared__ ushort xl[128 * 256];              // 64 KB
    __shared__ ushort wl[128 * 256];              // 64 KB
    const int which = blockIdx.y;
    const float* X = (which == 0) ? Q : (which == 1) ? K : V;
    const float* W = (which == 0) ? WQ : (which == 1) ? WK : WV;

    const int tid = threadIdx.x;
    const int wv = tid >> 6, lane = tid & 63;
    const int l31 = lane & 31, hi = lane >> 5;
    const int rg = blockIdx.x >> 1;               // 32 row-groups of 128
    const int cg = blockIdx.x & 1;                // 2 col-groups of 128
    const int n0 = cg * 128;

    {
        const float* xs = X + (size_t)rg * 128 * IN_D;
        const int ch = tid & 31;                  // chunk 0..31 (k-offset ch*8)
#pragma unroll
        for (int it = 0; it < 4; ++it) {
            const int row = (tid >> 5) + 32 * it;
            const float* xp = xs + (size_t)row * IN_D + ch * 8;
            const f4v x0 = *(const f4v*)xp;
            const f4v x1 = *(const f4v*)(xp + 4);
            union { unsigned u[4]; s8v v; } au;
            asm("v_cvt_pk_bf16_f32 %0, %1, %2" : "=v"(au.u[0]) : "v"(x0[0]), "v"(x0[1]));
            asm("v_cvt_pk_bf16_f32 %0, %1, %2" : "=v"(au.u[1]) : "v"(x0[2]), "v"(x0[3]));
            asm("v_cvt_pk_bf16_f32 %0, %1, %2" : "=v"(au.u[2]) : "v"(x1[0]), "v"(x1[1]));
            asm("v_cvt_pk_bf16_f32 %0, %1, %2" : "=v"(au.u[3]) : "v"(x1[2]), "v"(x1[3]));
            *(s8v*)&xl[row * 256 + ((ch ^ (row & 31)) * 8)] = au.v;
        }
    }
    {
        const int c4 = (tid & 31) * 4;            // col 0,4,..,124
#pragma unroll
        for (int it = 0; it < 8; ++it) {
            const int k = (tid >> 5) * 8 + it;    // 0..255
            const f4v w4 = *(const f4v*)(W + (size_t)k * (NHEAD * HDIM) + n0 + c4);
#pragma unroll
            for (int j = 0; j < 4; ++j) {
                const int col = c4 + j;
                wl[col * 256 + ((k >> 3) ^ (col & 31)) * 8 + (k & 7)] = f2b(w4[j]);
            }
        }
    }
    __syncthreads();

    const int rt2 = wv >> 2, ct2 = wv & 3;        // 4x4 sub-tiles of 32x32

    f16v acc = {};
#pragma unroll 4
    for (int ks = 0; ks < 16; ++ks) {
        const int pos = (2 * ks + hi) ^ l31;      // row&31 == l31 for both operands
        const s8v a = *(const s8v*)&xl[(rt2 * 32 + l31) * 256 + pos * 8];
        const s8v b = *(const s8v*)&wl[(ct2 * 32 + l31) * 256 + pos * 8];
        acc = __builtin_amdgcn_mfma_f32_32x32x16_bf16(a, b, acc, 0, 0, 0);
    }

    const int rt  = rg * 4 + rt2;
    const int qbt = rt & 63;
    const int bI  = rt >> 6;
    const int n = n0 + ct2 * 32 + l31;
    const int h = n >> 4, d = n & 15;
    const int bh = bI * NHEAD + h;
    if (which == 2) {
        ushort* vb = vt + (size_t)bh * 32768 + qbt * 512 + d * 8 + 4 * hi;
#pragma unroll
        for (int g2 = 0; g2 < 4; ++g2) {          // regs 4g..4g+3 -> j consecutive
            unsigned long long pk = 0;
#pragma unroll
            for (int j = 0; j < 4; ++j)
                pk |= (unsigned long long)f2b(acc[g2 * 4 + j]) << (16 * j);
            *(unsigned long long*)(vb + (g2 >> 1) * 256 + (g2 & 1) * 128) = pk;
        }
    } else {
        ushort* dst = ((which == 0) ? qh : kh) +
                      (size_t)bh * 32768 + qbt * 512 + (d >> 3) * 256 + (d & 7);
        const float scale = (which == 0) ? 0.25f * 1.44269504f : 1.0f;  // 1/sqrt(D)*log2e
#pragma unroll
        for (int r = 0; r < 16; ++r) {
            const int l31s = (r & 3) + 8 * (r >> 2) + 4 * hi;
            dst[l31s * 8] = f2b(acc[r] * scale);
        }
    }
}

// ---- causal attention: R20 body; ONE change: 6 waves/block (384 thr) ----
// __launch_bounds__(384,6): VGPR cap ~80 >= the 64 the body needs (no spill, unlike
// R21's 8-wave cap). 1024 blocks x 6 waves = 24 waves/CU = 6 waves/SIMD (vs R20's 4).
// Items strided over 6 waves (step 12, 10-11 items each). XCD mapping unchanged.
__global__ __launch_bounds__(384, 6) void attn_kernel(
    const ushort* __restrict__ qh, const ushort* __restrict__ kh,
    const ushort* __restrict__ vt, float* __restrict__ out)
{
    __shared__ float ol[2][6][8][64];             // 24 KB
    __shared__ float ll[2][6][32];                // 1.5 KB
    const int tid = threadIdx.x;
    const int wv = tid >> 6, lane = tid & 63;     // wv = 0..5
    const int l31 = lane & 31, hi = lane >> 5;
    const int bid = blockIdx.x;
    const int bh  = (bid & 7) * 4 + (bid >> 8);   // inverse of the XCD mapping
    const int qbA = (bid >> 3) & 31;              // light stream
    const int qbB = 63 - qbA;                     // heavy stream
    const int ntA = qbA + 1, ntB = qbB + 1;       // ntA + ntB == 65

    const ushort* qp = qh + (size_t)bh * 32768;
    const ushort* kp = kh + (size_t)bh * 32768;
    const ushort* vp = vt + (size_t)bh * 32768;

    const s8v qfA = *(const s8v*)(qp + qbA * 512 + hi * 256 + l31 * 8);
    const s8v qfB = *(const s8v*)(qp + qbB * 512 + hi * 256 + l31 * 8);
    const f16v z16 = {};
    f16v aA0 = {}, aA1 = {}, aB0 = {}, aB1 = {};

    s8v vinit = {};
    if (l31 == 16 || l31 == 20) {
#pragma unroll
        for (int j = 0; j < 8; ++j) vinit[j] = (short)0x3F80;
    }

    auto process = [&](int it) {
        const bool isB = (it < ntB);            // block/wave-uniform
        const int t  = isB ? it : it - ntB;
        const s8v kf = *(const s8v*)(kp + t * 512 + hi * 256 + l31 * 8);
        s8v vf0 = vinit, vf1 = vinit;
        if (l31 < 16) {
            vf0 = *(const s8v*)(vp + t * 512 + hi * 128 + l31 * 8);
            vf1 = *(const s8v*)(vp + t * 512 + 256 + hi * 128 + l31 * 8);
        }
        const s8v qf = isB ? qfB : qfA;
        const int nt = isB ? ntB : ntA;
        const f16v st = __builtin_amdgcn_mfma_f32_32x32x16_bf16(kf, qf, z16, 0, 0, 0);
        float p[16];
#pragma unroll
        for (int r = 0; r < 16; ++r) p[r] = __builtin_amdgcn_exp2f(st[r]);
        if (t == nt - 1) {                      // diagonal tile: zero k > q
#pragma unroll
            for (int r = 0; r < 16; ++r) {
                const int kr = (r & 3) + 8 * (r >> 2) + 4 * hi;
                if (kr > l31) p[r] = 0.f;
            }
        }
        s8v pb[2];
#pragma unroll
        for (int half = 0; half < 2; ++half) {
            unsigned x0, x1, y0, y1;
            asm("v_cvt_pk_bf16_f32 %0, %1, %2" : "=v"(x0) : "v"(p[8*half+0]), "v"(p[8*half+1]));
            asm("v_cvt_pk_bf16_f32 %0, %1, %2" : "=v"(x1) : "v"(p[8*half+2]), "v"(p[8*half+3]));
            asm("v_cvt_pk_bf16_f32 %0, %1, %2" : "=v"(y0) : "v"(p[8*half+4]), "v"(p[8*half+5]));
            asm("v_cvt_pk_bf16_f32 %0, %1, %2" : "=v"(y1) : "v"(p[8*half+6]), "v"(p[8*half+7]));
            auto r0 = __builtin_amdgcn_permlane32_swap(x0, y0, false, false);
            auto r1 = __builtin_amdgcn_permlane32_swap(x1, y1, false, false);
            union { unsigned u[4]; s8v v; } bu;
            bu.u[0] = r0[0]; bu.u[1] = r1[0]; bu.u[2] = r0[1]; bu.u[3] = r1[1];
            pb[half] = bu.v;
        }
        __builtin_amdgcn_s_setprio(1);
        if (isB) {
            aB0 = __builtin_amdgcn_mfma_f32_32x32x16_bf16(vf0, pb[0], aB0, 0, 0, 0);
            aB1 = __builtin_amdgcn_mfma_f32_32x32x16_bf16(vf1, pb[1], aB1, 0, 0, 0);
        } else {
            aA0 = __builtin_amdgcn_mfma_f32_32x32x16_bf16(vf0, pb[0], aA0, 0, 0, 0);
            aA1 = __builtin_amdgcn_mfma_f32_32x32x16_bf16(vf1, pb[1], aA1, 0, 0, 0);
        }
        __builtin_amdgcn_s_setprio(0);
    };

    for (int it0 = 2 * wv; it0 < 65; it0 += 12) {  // 6 waves stride the 65-item list
        process(it0);
        if (it0 + 1 < 65) process(it0 + 1);
    }

#pragma unroll
    for (int j = 0; j < 8; ++j) {
        ol[0][wv][j][lane] = aB0[j] + aB1[j];
        ol[1][wv][j][lane] = aA0[j] + aA1[j];
    }
    if (hi == 0) {
        ll[0][wv][l31] = aB0[8] + aB1[8];
        ll[1][wv][l31] = aA0[8] + aA1[8];
    }
    __syncthreads();

    if (wv < 2) {                               // wave 0 -> stream B, wave 1 -> stream A
        const int ss = wv;
        const int qw = (ss ? qbA : qbB) * 32;
        float l = ((ll[ss][0][l31] + ll[ss][1][l31]) + (ll[ss][2][l31] + ll[ss][3][l31]))
                + (ll[ss][4][l31] + ll[ss][5][l31]);
        const float inv = __builtin_amdgcn_rcpf(l);
        float o[8];
#pragma unroll
        for (int j = 0; j < 8; ++j)
            o[j] = (((ol[ss][0][j][lane] + ol[ss][1][j][lane]) +
                     (ol[ss][2][j][lane] + ol[ss][3][j][lane])) +
                    (ol[ss][4][j][lane] + ol[ss][5][j][lane])) * inv;
        const int b = bh >> 4, h = bh & 15;
        f4v o0, o1;
#pragma unroll
        for (int j = 0; j < 4; ++j) { o0[j] = o[j]; o1[j] = o[4 + j]; }
        float* op = out + ((size_t)b * S_LEN + qw + l31) * (NHEAD * HDIM) + h * HDIM;
        *(f4v*)(op + 4 * hi) = o0;        // d = 4*hi + 0..3
        *(f4v*)(op + 8 + 4 * hi) = o1;    // d = 8 + 4*hi + 0..3
    }
}

extern "C" void kernel_launch(void* const* d_in, const int* in_sizes, int n_in,
                              void* d_out, int out_size, void* d_ws, size_t ws_size,
                              hipStream_t stream)
{
    const float* Q  = (const float*)d_in[0];
    const float* K  = (const float*)d_in[1];
    const float* V  = (const float*)d_in[2];
    const float* WQ = (const float*)d_in[3];
    const float* WK = (const float*)d_in[4];
    const float* WV = (const float*)d_in[5];
    float* out = (float*)d_out;

    const size_t mat = (size_t)2 * NHEAD * S_LEN * HDIM;   // 2 MB bf16 each
    ushort* qh = (ushort*)d_ws;
    ushort* kh = qh + mat;
    ushort* vt = kh + mat;

    proj_kernel<<<dim3(64, 3), 1024, 0, stream>>>(Q, K, V, WQ, WK, WV, qh, kh, vt);
    attn_kernel<<<dim3(1024), 384, 0, stream>>>(qh, kh, vt, out);
}

// Round 23
// 37.058 us; speedup vs baseline: 4.5584x; 3.4239x over previous
//
#include <hip/hip_runtime.h>
#include <hip/hip_bf16.h>

#define S_LEN 2048
#define IN_D  256
#define NHEAD 16
#define HDIM  16

typedef short s8v __attribute__((ext_vector_type(8)));
typedef float f4v __attribute__((ext_vector_type(4)));
typedef float f16v __attribute__((ext_vector_type(16)));

__device__ __forceinline__ ushort f2b(float f) {
    union { float f; unsigned u; } x; x.f = f;
    unsigned r = x.u + 0x7fffu + ((x.u >> 16) & 1u);   // RNE, inputs finite
    return (ushort)(r >> 16);
}

// ---- fragment-order layouts (all attn loads wave-contiguous) ----
// qh [bh][qb(64)][hi(2)][l31(32)][j(8)]  (pre-scaled by 0.25*log2e)
// kh [bh][t (64)][hi(2)][l31(32)][j(8)]
// vt [bh][t (64)][half(2)][hi(2)][d(16)][j(8)]

// -------- projection: 128x128 tile, 16 waves, X+W LDS with XOR chunk swizzle --------
// (byte-identical to R18/R20) conflict-free ds_read_b128; staging fully coalesced.
__global__ __launch_bounds__(1024, 4) void proj_kernel(
    const float* __restrict__ Q, const float* __restrict__ K, const float* __restrict__ V,
    const float* __restrict__ WQ, const float* __restrict__ WK, const float* __restrict__ WV,
    ushort* __restrict__ qh, ushort* __restrict__ kh, ushort* __restrict__ vt)
{
    __shared__ ushort xl[128 * 256];              // 64 KB
    __shared__ ushort wl[128 * 256];              // 64 KB
    const int which = blockIdx.y;
    const float* X = (which == 0) ? Q : (which == 1) ? K : V;
    const float* W = (which == 0) ? WQ : (which == 1) ? WK : WV;

    const int tid = threadIdx.x;
    const int wv = tid >> 6, lane = tid & 63;
    const int l31 = lane & 31, hi = lane >> 5;
    const int rg = blockIdx.x >> 1;               // 32 row-groups of 128
    const int cg = blockIdx.x & 1;                // 2 col-groups of 128
    const int n0 = cg * 128;

    {
        const float* xs = X + (size_t)rg * 128 * IN_D;
        const int ch = tid & 31;                  // chunk 0..31 (k-offset ch*8)
#pragma unroll
        for (int it = 0; it < 4; ++it) {
            const int row = (tid >> 5) + 32 * it;
            const float* xp = xs + (size_t)row * IN_D + ch * 8;
            const f4v x0 = *(const f4v*)xp;
            const f4v x1 = *(const f4v*)(xp + 4);
            union { unsigned u[4]; s8v v; } au;
            asm("v_cvt_pk_bf16_f32 %0, %1, %2" : "=v"(au.u[0]) : "v"(x0[0]), "v"(x0[1]));
            asm("v_cvt_pk_bf16_f32 %0, %1, %2" : "=v"(au.u[1]) : "v"(x0[2]), "v"(x0[3]));
            asm("v_cvt_pk_bf16_f32 %0, %1, %2" : "=v"(au.u[2]) : "v"(x1[0]), "v"(x1[1]));
            asm("v_cvt_pk_bf16_f32 %0, %1, %2" : "=v"(au.u[3]) : "v"(x1[2]), "v"(x1[3]));
            *(s8v*)&xl[row * 256 + ((ch ^ (row & 31)) * 8)] = au.v;
        }
    }
    {
        const int c4 = (tid & 31) * 4;            // col 0,4,..,124
#pragma unroll
        for (int it = 0; it < 8; ++it) {
            const int k = (tid >> 5) * 8 + it;    // 0..255
            const f4v w4 = *(const f4v*)(W + (size_t)k * (NHEAD * HDIM) + n0 + c4);
#pragma unroll
            for (int j = 0; j < 4; ++j) {
                const int col = c4 + j;
                wl[col * 256 + ((k >> 3) ^ (col & 31)) * 8 + (k & 7)] = f2b(w4[j]);
            }
        }
    }
    __syncthreads();

    const int rt2 = wv >> 2, ct2 = wv & 3;        // 4x4 sub-tiles of 32x32

    f16v acc = {};
#pragma unroll 4
    for (int ks = 0; ks < 16; ++ks) {
        const int pos = (2 * ks + hi) ^ l31;      // row&31 == l31 for both operands
        const s8v a = *(const s8v*)&xl[(rt2 * 32 + l31) * 256 + pos * 8];
        const s8v b = *(const s8v*)&wl[(ct2 * 32 + l31) * 256 + pos * 8];
        acc = __builtin_amdgcn_mfma_f32_32x32x16_bf16(a, b, acc, 0, 0, 0);
    }

    const int rt  = rg * 4 + rt2;
    const int qbt = rt & 63;
    const int bI  = rt >> 6;
    const int n = n0 + ct2 * 32 + l31;
    const int h = n >> 4, d = n & 15;
    const int bh = bI * NHEAD + h;
    if (which == 2) {
        ushort* vb = vt + (size_t)bh * 32768 + qbt * 512 + d * 8 + 4 * hi;
#pragma unroll
        for (int g2 = 0; g2 < 4; ++g2) {          // regs 4g..4g+3 -> j consecutive
            unsigned long long pk = 0;
#pragma unroll
            for (int j = 0; j < 4; ++j)
                pk |= (unsigned long long)f2b(acc[g2 * 4 + j]) << (16 * j);
            *(unsigned long long*)(vb + (g2 >> 1) * 256 + (g2 & 1) * 128) = pk;
        }
    } else {
        ushort* dst = ((which == 0) ? qh : kh) +
                      (size_t)bh * 32768 + qbt * 512 + (d >> 3) * 256 + (d & 7);
        const float scale = (which == 0) ? 0.25f * 1.44269504f : 1.0f;  // 1/sqrt(D)*log2e
#pragma unroll
        for (int r = 0; r < 16; ++r) {
            const int l31s = (r & 3) + 8 * (r >> 2) + 4 * hi;
            dst[l31s * 8] = f2b(acc[r] * scale);
        }
    }
}

// ---- causal attention: R20 body EXACTLY; ONE change: __launch_bounds__(256) only ----
// No min-waves arg -> no 64-VGPR cap (compiler cap model: 256/min_waves; R21/R22's
// spills were cap artifacts). Natural allocation ~72-96 VGPR -> no spill; HW pool
// 512/SIMD (m69) -> 5-7 waves/SIMD if <=102 VGPR, never worse than R20's 4.
__global__ __launch_bounds__(256) void attn_kernel(
    const ushort* __restrict__ qh, const ushort* __restrict__ kh,
    const ushort* __restrict__ vt, float* __restrict__ out)
{
    __shared__ float ol[2][4][8][64];
    __shared__ float ll[2][4][32];
    const int tid = threadIdx.x;
    const int wv = tid >> 6, lane = tid & 63;
    const int l31 = lane & 31, hi = lane >> 5;
    const int bid = blockIdx.x;
    const int bh  = (bid & 7) * 4 + (bid >> 8);   // inverse of the XCD mapping
    const int qbA = (bid >> 3) & 31;              // light stream
    const int qbB = 63 - qbA;                     // heavy stream
    const int ntA = qbA + 1, ntB = qbB + 1;       // ntA + ntB == 65

    const ushort* qp = qh + (size_t)bh * 32768;
    const ushort* kp = kh + (size_t)bh * 32768;
    const ushort* vp = vt + (size_t)bh * 32768;

    const s8v qfA = *(const s8v*)(qp + qbA * 512 + hi * 256 + l31 * 8);
    const s8v qfB = *(const s8v*)(qp + qbB * 512 + hi * 256 + l31 * 8);
    const f16v z16 = {};
    f16v aA0 = {}, aA1 = {}, aB0 = {}, aB1 = {};

    s8v vinit = {};
    if (l31 == 16 || l31 == 20) {
#pragma unroll
        for (int j = 0; j < 8; ++j) vinit[j] = (short)0x3F80;
    }

    auto process = [&](int it) {
        const bool isB = (it < ntB);            // block/wave-uniform
        const int t  = isB ? it : it - ntB;
        const s8v kf = *(const s8v*)(kp + t * 512 + hi * 256 + l31 * 8);
        s8v vf0 = vinit, vf1 = vinit;
        if (l31 < 16) {
            vf0 = *(const s8v*)(vp + t * 512 + hi * 128 + l31 * 8);
            vf1 = *(const s8v*)(vp + t * 512 + 256 + hi * 128 + l31 * 8);
        }
        const s8v qf = isB ? qfB : qfA;
        const int nt = isB ? ntB : ntA;
        const f16v st = __builtin_amdgcn_mfma_f32_32x32x16_bf16(kf, qf, z16, 0, 0, 0);
        float p[16];
#pragma unroll
        for (int r = 0; r < 16; ++r) p[r] = __builtin_amdgcn_exp2f(st[r]);
        if (t == nt - 1) {                      // diagonal tile: zero k > q
#pragma unroll
            for (int r = 0; r < 16; ++r) {
                const int kr = (r & 3) + 8 * (r >> 2) + 4 * hi;
                if (kr > l31) p[r] = 0.f;
            }
        }
        s8v pb[2];
#pragma unroll
        for (int half = 0; half < 2; ++half) {
            unsigned x0, x1, y0, y1;
            asm("v_cvt_pk_bf16_f32 %0, %1, %2" : "=v"(x0) : "v"(p[8*half+0]), "v"(p[8*half+1]));
            asm("v_cvt_pk_bf16_f32 %0, %1, %2" : "=v"(x1) : "v"(p[8*half+2]), "v"(p[8*half+3]));
            asm("v_cvt_pk_bf16_f32 %0, %1, %2" : "=v"(y0) : "v"(p[8*half+4]), "v"(p[8*half+5]));
            asm("v_cvt_pk_bf16_f32 %0, %1, %2" : "=v"(y1) : "v"(p[8*half+6]), "v"(p[8*half+7]));
            auto r0 = __builtin_amdgcn_permlane32_swap(x0, y0, false, false);
            auto r1 = __builtin_amdgcn_permlane32_swap(x1, y1, false, false);
            union { unsigned u[4]; s8v v; } bu;
            bu.u[0] = r0[0]; bu.u[1] = r1[0]; bu.u[2] = r0[1]; bu.u[3] = r1[1];
            pb[half] = bu.v;
        }
        __builtin_amdgcn_s_setprio(1);
        if (isB) {
            aB0 = __builtin_amdgcn_mfma_f32_32x32x16_bf16(vf0, pb[0], aB0, 0, 0, 0);
            aB1 = __builtin_amdgcn_mfma_f32_32x32x16_bf16(vf1, pb[1], aB1, 0, 0, 0);
        } else {
            aA0 = __builtin_amdgcn_mfma_f32_32x32x16_bf16(vf0, pb[0], aA0, 0, 0, 0);
            aA1 = __builtin_amdgcn_mfma_f32_32x32x16_bf16(vf1, pb[1], aA1, 0, 0, 0);
        }
        __builtin_amdgcn_s_setprio(0);
    };

    for (int it0 = 2 * wv; it0 < 65; it0 += 8) {   // two independent items per iteration
        process(it0);
        if (it0 + 1 < 65) process(it0 + 1);
    }

#pragma unroll
    for (int j = 0; j < 8; ++j) {
        ol[0][wv][j][lane] = aB0[j] + aB1[j];
        ol[1][wv][j][lane] = aA0[j] + aA1[j];
    }
    if (hi == 0) {
        ll[0][wv][l31] = aB0[8] + aB1[8];
        ll[1][wv][l31] = aA0[8] + aA1[8];
    }
    __syncthreads();

    if (wv < 2) {                               // wave 0 -> stream B, wave 1 -> stream A
        const int ss = wv;
        const int qw = (ss ? qbA : qbB) * 32;
        float l = (ll[ss][0][l31] + ll[ss][1][l31]) + (ll[ss][2][l31] + ll[ss][3][l31]);
        const float inv = __builtin_amdgcn_rcpf(l);
        float o[8];
#pragma unroll
        for (int j = 0; j < 8; ++j)
            o[j] = ((ol[ss][0][j][lane] + ol[ss][1][j][lane]) +
                    (ol[ss][2][j][lane] + ol[ss][3][j][lane])) * inv;
        const int b = bh >> 4, h = bh & 15;
        f4v o0, o1;
#pragma unroll
        for (int j = 0; j < 4; ++j) { o0[j] = o[j]; o1[j] = o[4 + j]; }
        float* op = out + ((size_t)b * S_LEN + qw + l31) * (NHEAD * HDIM) + h * HDIM;
        *(f4v*)(op + 4 * hi) = o0;        // d = 4*hi + 0..3
        *(f4v*)(op + 8 + 4 * hi) = o1;    // d = 8 + 4*hi + 0..3
    }
}

extern "C" void kernel_launch(void* const* d_in, const int* in_sizes, int n_in,
                              void* d_out, int out_size, void* d_ws, size_t ws_size,
                              hipStream_t stream)
{
    const float* Q  = (const float*)d_in[0];
    const float* K  = (const float*)d_in[1];
    const float* V  = (const float*)d_in[2];
    const float* WQ = (const float*)d_in[3];
    const float* WK = (const float*)d_in[4];
    const float* WV = (const float*)d_in[5];
    float* out = (float*)d_out;

    const size_t mat = (size_t)2 * NHEAD * S_LEN * HDIM;   // 2 MB bf16 each
    ushort* qh = (ushort*)d_ws;
    ushort* kh = qh + mat;
    ushort* vt = kh + mat;

    proj_kernel<<<dim3(64, 3), 1024, 0, stream>>>(Q, K, V, WQ, WK, WV, qh, kh, vt);
    attn_kernel<<<dim3(1024), 256, 0, stream>>>(qh, kh, vt, out);
}

// Round 24
// 26.767 us; speedup vs baseline: 6.3110x; 1.3845x over previous
//
#include <hip/hip_runtime.h>
#include <hip/hip_bf16.h>

#define S_LEN 2048
#define IN_D  256
#define NHEAD 16
#define HDIM  16

typedef short s8v __attribute__((ext_vector_type(8)));
typedef float f4v __attribute__((ext_vector_type(4)));
typedef float f16v __attribute__((ext_vector_type(16)));

__device__ __forceinline__ ushort f2b(float f) {
    union { float f; unsigned u; } x; x.f = f;
    unsigned r = x.u + 0x7fffu + ((x.u >> 16) & 1u);   // RNE, inputs finite
    return (ushort)(r >> 16);
}

// ---- fragment-order layouts (all attn loads wave-contiguous) ----
// qh [bh][qb(64)][hi(2)][l31(32)][j(8)]  (pre-scaled by 0.25*log2e)
// kh [bh][t (64)][hi(2)][l31(32)][j(8)]
// vt [bh][t (64)][half(2)][hi(2)][d(16)][j(8)]

// -------- projection: 128x128 tile, 16 waves, X+W LDS with XOR chunk swizzle --------
// (byte-identical to R18/R20) conflict-free ds_read_b128; staging fully coalesced.
__global__ __launch_bounds__(1024, 4) void proj_kernel(
    const float* __restrict__ Q, const float* __restrict__ K, const float* __restrict__ V,
    const float* __restrict__ WQ, const float* __restrict__ WK, const float* __restrict__ WV,
    ushort* __restrict__ qh, ushort* __restrict__ kh, ushort* __restrict__ vt)
{
    __shared__ ushort xl[128 * 256];              // 64 KB
    __shared__ ushort wl[128 * 256];              // 64 KB
    const int which = blockIdx.y;
    const float* X = (which == 0) ? Q : (which == 1) ? K : V;
    const float* W = (which == 0) ? WQ : (which == 1) ? WK : WV;

    const int tid = threadIdx.x;
    const int wv = tid >> 6, lane = tid & 63;
    const int l31 = lane & 31, hi = lane >> 5;
    const int rg = blockIdx.x >> 1;               // 32 row-groups of 128
    const int cg = blockIdx.x & 1;                // 2 col-groups of 128
    const int n0 = cg * 128;

    {
        const float* xs = X + (size_t)rg * 128 * IN_D;
        const int ch = tid & 31;                  // chunk 0..31 (k-offset ch*8)
#pragma unroll
        for (int it = 0; it < 4; ++it) {
            const int row = (tid >> 5) + 32 * it;
            const float* xp = xs + (size_t)row * IN_D + ch * 8;
            const f4v x0 = *(const f4v*)xp;
            const f4v x1 = *(const f4v*)(xp + 4);
            union { unsigned u[4]; s8v v; } au;
            asm("v_cvt_pk_bf16_f32 %0, %1, %2" : "=v"(au.u[0]) : "v"(x0[0]), "v"(x0[1]));
            asm("v_cvt_pk_bf16_f32 %0, %1, %2" : "=v"(au.u[1]) : "v"(x0[2]), "v"(x0[3]));
            asm("v_cvt_pk_bf16_f32 %0, %1, %2" : "=v"(au.u[2]) : "v"(x1[0]), "v"(x1[1]));
            asm("v_cvt_pk_bf16_f32 %0, %1, %2" : "=v"(au.u[3]) : "v"(x1[2]), "v"(x1[3]));
            *(s8v*)&xl[row * 256 + ((ch ^ (row & 31)) * 8)] = au.v;
        }
    }
    {
        const int c4 = (tid & 31) * 4;            // col 0,4,..,124
#pragma unroll
        for (int it = 0; it < 8; ++it) {
            const int k = (tid >> 5) * 8 + it;    // 0..255
            const f4v w4 = *(const f4v*)(W + (size_t)k * (NHEAD * HDIM) + n0 + c4);
#pragma unroll
            for (int j = 0; j < 4; ++j) {
                const int col = c4 + j;
                wl[col * 256 + ((k >> 3) ^ (col & 31)) * 8 + (k & 7)] = f2b(w4[j]);
            }
        }
    }
    __syncthreads();

    const int rt2 = wv >> 2, ct2 = wv & 3;        // 4x4 sub-tiles of 32x32

    f16v acc = {};
#pragma unroll 4
    for (int ks = 0; ks < 16; ++ks) {
        const int pos = (2 * ks + hi) ^ l31;      // row&31 == l31 for both operands
        const s8v a = *(const s8v*)&xl[(rt2 * 32 + l31) * 256 + pos * 8];
        const s8v b = *(const s8v*)&wl[(ct2 * 32 + l31) * 256 + pos * 8];
        acc = __builtin_amdgcn_mfma_f32_32x32x16_bf16(a, b, acc, 0, 0, 0);
    }

    const int rt  = rg * 4 + rt2;
    const int qbt = rt & 63;
    const int bI  = rt >> 6;
    const int n = n0 + ct2 * 32 + l31;
    const int h = n >> 4, d = n & 15;
    const int bh = bI * NHEAD + h;
    if (which == 2) {
        ushort* vb = vt + (size_t)bh * 32768 + qbt * 512 + d * 8 + 4 * hi;
#pragma unroll
        for (int g2 = 0; g2 < 4; ++g2) {          // regs 4g..4g+3 -> j consecutive
            unsigned long long pk = 0;
#pragma unroll
            for (int j = 0; j < 4; ++j)
                pk |= (unsigned long long)f2b(acc[g2 * 4 + j]) << (16 * j);
            *(unsigned long long*)(vb + (g2 >> 1) * 256 + (g2 & 1) * 128) = pk;
        }
    } else {
        ushort* dst = ((which == 0) ? qh : kh) +
                      (size_t)bh * 32768 + qbt * 512 + (d >> 3) * 256 + (d & 7);
        const float scale = (which == 0) ? 0.25f * 1.44269504f : 1.0f;  // 1/sqrt(D)*log2e
#pragma unroll
        for (int r = 0; r < 16; ++r) {
            const int l31s = (r & 3) + 8 * (r >> 2) + 4 * hi;
            dst[l31s * 8] = f2b(acc[r] * scale);
        }
    }
}

// ---- causal attention: R20 config (256 thr, (256,4), XCD map); ONE change: ----
// work item = k-tile t (0..ntB-1). Stream A's tiles are a SUBSET of stream B's, so
// each tile's K/V is loaded ONCE and feeds stream B always + stream A when t < ntA
// (wave-uniform). ~25% fewer global loads & address math vs the 65-item list.
__global__ __launch_bounds__(256, 4) void attn_kernel(
    const ushort* __restrict__ qh, const ushort* __restrict__ kh,
    const ushort* __restrict__ vt, float* __restrict__ out)
{
    __shared__ float ol[2][4][8][64];
    __shared__ float ll[2][4][32];
    const int tid = threadIdx.x;
    const int wv = tid >> 6, lane = tid & 63;
    const int l31 = lane & 31, hi = lane >> 5;
    const int bid = blockIdx.x;
    const int bh  = (bid & 7) * 4 + (bid >> 8);   // inverse of the XCD mapping
    const int qbA = (bid >> 3) & 31;              // light stream
    const int qbB = 63 - qbA;                     // heavy stream
    const int ntA = qbA + 1, ntB = qbB + 1;       // ntA + ntB == 65

    const ushort* qp = qh + (size_t)bh * 32768;
    const ushort* kp = kh + (size_t)bh * 32768;
    const ushort* vp = vt + (size_t)bh * 32768;

    const s8v qfA = *(const s8v*)(qp + qbA * 512 + hi * 256 + l31 * 8);
    const s8v qfB = *(const s8v*)(qp + qbB * 512 + hi * 256 + l31 * 8);
    const f16v z16 = {};
    f16v aA0 = {}, aA1 = {}, aB0 = {}, aB1 = {};

    s8v vinit = {};
    if (l31 == 16 || l31 == 20) {
#pragma unroll
        for (int j = 0; j < 8; ++j) vinit[j] = (short)0x3F80;
    }

    // one stream's QK -> softmax -> PV given the shared K/V fragments
    auto stream_step = [&](bool isB, int t, int nt,
                           const s8v& kf, const s8v& vf0, const s8v& vf1) {
        const f16v st = __builtin_amdgcn_mfma_f32_32x32x16_bf16(kf, isB ? qfB : qfA,
                                                                z16, 0, 0, 0);
        float p[16];
#pragma unroll
        for (int r = 0; r < 16; ++r) p[r] = __builtin_amdgcn_exp2f(st[r]);
        if (t == nt - 1) {                      // diagonal tile: zero k > q
#pragma unroll
            for (int r = 0; r < 16; ++r) {
                const int kr = (r & 3) + 8 * (r >> 2) + 4 * hi;
                if (kr > l31) p[r] = 0.f;
            }
        }
        s8v pb[2];
#pragma unroll
        for (int half = 0; half < 2; ++half) {
            unsigned x0, x1, y0, y1;
            asm("v_cvt_pk_bf16_f32 %0, %1, %2" : "=v"(x0) : "v"(p[8*half+0]), "v"(p[8*half+1]));
            asm("v_cvt_pk_bf16_f32 %0, %1, %2" : "=v"(x1) : "v"(p[8*half+2]), "v"(p[8*half+3]));
            asm("v_cvt_pk_bf16_f32 %0, %1, %2" : "=v"(y0) : "v"(p[8*half+4]), "v"(p[8*half+5]));
            asm("v_cvt_pk_bf16_f32 %0, %1, %2" : "=v"(y1) : "v"(p[8*half+6]), "v"(p[8*half+7]));
            auto r0 = __builtin_amdgcn_permlane32_swap(x0, y0, false, false);
            auto r1 = __builtin_amdgcn_permlane32_swap(x1, y1, false, false);
            union { unsigned u[4]; s8v v; } bu;
            bu.u[0] = r0[0]; bu.u[1] = r1[0]; bu.u[2] = r0[1]; bu.u[3] = r1[1];
            pb[half] = bu.v;
        }
        __builtin_amdgcn_s_setprio(1);
        if (isB) {
            aB0 = __builtin_amdgcn_mfma_f32_32x32x16_bf16(vf0, pb[0], aB0, 0, 0, 0);
            aB1 = __builtin_amdgcn_mfma_f32_32x32x16_bf16(vf1, pb[1], aB1, 0, 0, 0);
        } else {
            aA0 = __builtin_amdgcn_mfma_f32_32x32x16_bf16(vf0, pb[0], aA0, 0, 0, 0);
            aA1 = __builtin_amdgcn_mfma_f32_32x32x16_bf16(vf1, pb[1], aA1, 0, 0, 0);
        }
        __builtin_amdgcn_s_setprio(0);
    };

    auto tile = [&](int t) {
        const s8v kf = *(const s8v*)(kp + t * 512 + hi * 256 + l31 * 8);
        s8v vf0 = vinit, vf1 = vinit;
        if (l31 < 16) {
            vf0 = *(const s8v*)(vp + t * 512 + hi * 128 + l31 * 8);
            vf1 = *(const s8v*)(vp + t * 512 + 256 + hi * 128 + l31 * 8);
        }
        stream_step(true, t, ntB, kf, vf0, vf1);         // stream B: every tile
        if (t < ntA)                                     // stream A: shared K/V
            stream_step(false, t, ntA, kf, vf0, vf1);
    };

    for (int t0 = 2 * wv; t0 < ntB; t0 += 8) {    // two tiles/iteration for ILP
        tile(t0);
        if (t0 + 1 < ntB) tile(t0 + 1);
    }

#pragma unroll
    for (int j = 0; j < 8; ++j) {
        ol[0][wv][j][lane] = aB0[j] + aB1[j];
        ol[1][wv][j][lane] = aA0[j] + aA1[j];
    }
    if (hi == 0) {
        ll[0][wv][l31] = aB0[8] + aB1[8];
        ll[1][wv][l31] = aA0[8] + aA1[8];
    }
    __syncthreads();

    if (wv < 2) {                               // wave 0 -> stream B, wave 1 -> stream A
        const int ss = wv;
        const int qw = (ss ? qbA : qbB) * 32;
        float l = (ll[ss][0][l31] + ll[ss][1][l31]) + (ll[ss][2][l31] + ll[ss][3][l31]);
        const float inv = __builtin_amdgcn_rcpf(l);
        float o[8];
#pragma unroll
        for (int j = 0; j < 8; ++j)
            o[j] = ((ol[ss][0][j][lane] + ol[ss][1][j][lane]) +
                    (ol[ss][2][j][lane] + ol[ss][3][j][lane])) * inv;
        const int b = bh >> 4, h = bh & 15;
        f4v o0, o1;
#pragma unroll
        for (int j = 0; j < 4; ++j) { o0[j] = o[j]; o1[j] = o[4 + j]; }
        float* op = out + ((size_t)b * S_LEN + qw + l31) * (NHEAD * HDIM) + h * HDIM;
        *(f4v*)(op + 4 * hi) = o0;        // d = 4*hi + 0..3
        *(f4v*)(op + 8 + 4 * hi) = o1;    // d = 8 + 4*hi + 0..3
    }
}

extern "C" void kernel_launch(void* const* d_in, const int* in_sizes, int n_in,
                              void* d_out, int out_size, void* d_ws, size_t ws_size,
                              hipStream_t stream)
{
    const float* Q  = (const float*)d_in[0];
    const float* K  = (const float*)d_in[1];
    const float* V  = (const float*)d_in[2];
    const float* WQ = (const float*)d_in[3];
    const float* WK = (const float*)d_in[4];
    const float* WV = (const float*)d_in[5];
    float* out = (float*)d_out;

    const size_t mat = (size_t)2 * NHEAD * S_LEN * HDIM;   // 2 MB bf16 each
    ushort* qh = (ushort*)d_ws;
    ushort* kh = qh + mat;
    ushort* vt = kh + mat;

    proj_kernel<<<dim3(64, 3), 1024, 0, stream>>>(Q, K, V, WQ, WK, WV, qh, kh, vt);
    attn_kernel<<<dim3(1024), 256, 0, stream>>>(qh, kh, vt, out);
}

// Round 25
// 26.521 us; speedup vs baseline: 6.3694x; 1.0093x over previous
//
#include <hip/hip_runtime.h>
#include <hip/hip_bf16.h>

#define S_LEN 2048
#define IN_D  256
#define NHEAD 16
#define HDIM  16

typedef short s8v __attribute__((ext_vector_type(8)));
typedef float f4v __attribute__((ext_vector_type(4)));
typedef float f16v __attribute__((ext_vector_type(16)));

__device__ __forceinline__ ushort f2b(float f) {
    union { float f; unsigned u; } x; x.f = f;
    unsigned r = x.u + 0x7fffu + ((x.u >> 16) & 1u);   // RNE, inputs finite
    return (ushort)(r >> 16);
}

// ---- fragment-order layouts (all attn loads wave-contiguous) ----
// qh [bh][qb(64)][hi(2)][l31(32)][j(8)]  (pre-scaled by 0.25*log2e)
// kh [bh][t (64)][hi(2)][l31(32)][j(8)]
// vt [bh][t (64)][half(2)][hi(2)][d(16)][j(8)]

// -------- projection: 128x128 tile, 16 waves, X+W LDS with XOR chunk swizzle --------
// (byte-identical to R18/R20/R24) conflict-free ds_read_b128; staging fully coalesced.
__global__ __launch_bounds__(1024, 4) void proj_kernel(
    const float* __restrict__ Q, const float* __restrict__ K, const float* __restrict__ V,
    const float* __restrict__ WQ, const float* __restrict__ WK, const float* __restrict__ WV,
    ushort* __restrict__ qh, ushort* __restrict__ kh, ushort* __restrict__ vt)
{
    __shared__ ushort xl[128 * 256];              // 64 KB
    __shared__ ushort wl[128 * 256];              // 64 KB
    const int which = blockIdx.y;
    const float* X = (which == 0) ? Q : (which == 1) ? K : V;
    const float* W = (which == 0) ? WQ : (which == 1) ? WK : WV;

    const int tid = threadIdx.x;
    const int wv = tid >> 6, lane = tid & 63;
    const int l31 = lane & 31, hi = lane >> 5;
    const int rg = blockIdx.x >> 1;               // 32 row-groups of 128
    const int cg = blockIdx.x & 1;                // 2 col-groups of 128
    const int n0 = cg * 128;

    {
        const float* xs = X + (size_t)rg * 128 * IN_D;
        const int ch = tid & 31;                  // chunk 0..31 (k-offset ch*8)
#pragma unroll
        for (int it = 0; it < 4; ++it) {
            const int row = (tid >> 5) + 32 * it;
            const float* xp = xs + (size_t)row * IN_D + ch * 8;
            const f4v x0 = *(const f4v*)xp;
            const f4v x1 = *(const f4v*)(xp + 4);
            union { unsigned u[4]; s8v v; } au;
            asm("v_cvt_pk_bf16_f32 %0, %1, %2" : "=v"(au.u[0]) : "v"(x0[0]), "v"(x0[1]));
            asm("v_cvt_pk_bf16_f32 %0, %1, %2" : "=v"(au.u[1]) : "v"(x0[2]), "v"(x0[3]));
            asm("v_cvt_pk_bf16_f32 %0, %1, %2" : "=v"(au.u[2]) : "v"(x1[0]), "v"(x1[1]));
            asm("v_cvt_pk_bf16_f32 %0, %1, %2" : "=v"(au.u[3]) : "v"(x1[2]), "v"(x1[3]));
            *(s8v*)&xl[row * 256 + ((ch ^ (row & 31)) * 8)] = au.v;
        }
    }
    {
        const int c4 = (tid & 31) * 4;            // col 0,4,..,124
#pragma unroll
        for (int it = 0; it < 8; ++it) {
            const int k = (tid >> 5) * 8 + it;    // 0..255
            const f4v w4 = *(const f4v*)(W + (size_t)k * (NHEAD * HDIM) + n0 + c4);
#pragma unroll
            for (int j = 0; j < 4; ++j) {
                const int col = c4 + j;
                wl[col * 256 + ((k >> 3) ^ (col & 31)) * 8 + (k & 7)] = f2b(w4[j]);
            }
        }
    }
    __syncthreads();

    const int rt2 = wv >> 2, ct2 = wv & 3;        // 4x4 sub-tiles of 32x32

    f16v acc = {};
#pragma unroll 4
    for (int ks = 0; ks < 16; ++ks) {
        const int pos = (2 * ks + hi) ^ l31;      // row&31 == l31 for both operands
        const s8v a = *(const s8v*)&xl[(rt2 * 32 + l31) * 256 + pos * 8];
        const s8v b = *(const s8v*)&wl[(ct2 * 32 + l31) * 256 + pos * 8];
        acc = __builtin_amdgcn_mfma_f32_32x32x16_bf16(a, b, acc, 0, 0, 0);
    }

    const int rt  = rg * 4 + rt2;
    const int qbt = rt & 63;
    const int bI  = rt >> 6;
    const int n = n0 + ct2 * 32 + l31;
    const int h = n >> 4, d = n & 15;
    const int bh = bI * NHEAD + h;
    if (which == 2) {
        ushort* vb = vt + (size_t)bh * 32768 + qbt * 512 + d * 8 + 4 * hi;
#pragma unroll
        for (int g2 = 0; g2 < 4; ++g2) {          // regs 4g..4g+3 -> j consecutive
            unsigned long long pk = 0;
#pragma unroll
            for (int j = 0; j < 4; ++j)
                pk |= (unsigned long long)f2b(acc[g2 * 4 + j]) << (16 * j);
            *(unsigned long long*)(vb + (g2 >> 1) * 256 + (g2 & 1) * 128) = pk;
        }
    } else {
        ushort* dst = ((which == 0) ? qh : kh) +
                      (size_t)bh * 32768 + qbt * 512 + (d >> 3) * 256 + (d & 7);
        const float scale = (which == 0) ? 0.25f * 1.44269504f : 1.0f;  // 1/sqrt(D)*log2e
#pragma unroll
        for (int r = 0; r < 16; ++r) {
            const int l31s = (r & 3) + 8 * (r >> 2) + 4 * hi;
            dst[l31s * 8] = f2b(acc[r] * scale);
        }
    }
}

// ---- causal attention: R24 body; ONE change: s_setprio removed ----
// A/B: m190 measured setprio HURTING in the multi-wave-per-SIMD contention regime
// (our config: 4 blocks/CU, waves at independent phases); m191's +7% was the
// isolated-wave regime. Also removes 2 SALU/step (130/block).
__global__ __launch_bounds__(256, 4) void attn_kernel(
    const ushort* __restrict__ qh, const ushort* __restrict__ kh,
    const ushort* __restrict__ vt, float* __restrict__ out)
{
    __shared__ float ol[2][4][8][64];
    __shared__ float ll[2][4][32];
    const int tid = threadIdx.x;
    const int wv = tid >> 6, lane = tid & 63;
    const int l31 = lane & 31, hi = lane >> 5;
    const int bid = blockIdx.x;
    const int bh  = (bid & 7) * 4 + (bid >> 8);   // inverse of the XCD mapping
    const int qbA = (bid >> 3) & 31;              // light stream
    const int qbB = 63 - qbA;                     // heavy stream
    const int ntA = qbA + 1, ntB = qbB + 1;       // ntA + ntB == 65

    const ushort* qp = qh + (size_t)bh * 32768;
    const ushort* kp = kh + (size_t)bh * 32768;
    const ushort* vp = vt + (size_t)bh * 32768;

    const s8v qfA = *(const s8v*)(qp + qbA * 512 + hi * 256 + l31 * 8);
    const s8v qfB = *(const s8v*)(qp + qbB * 512 + hi * 256 + l31 * 8);
    const f16v z16 = {};
    f16v aA0 = {}, aA1 = {}, aB0 = {}, aB1 = {};

    s8v vinit = {};
    if (l31 == 16 || l31 == 20) {
#pragma unroll
        for (int j = 0; j < 8; ++j) vinit[j] = (short)0x3F80;
    }

    // one stream's QK -> softmax -> PV given the shared K/V fragments
    auto stream_step = [&](bool isB, int t, int nt,
                           const s8v& kf, const s8v& vf0, const s8v& vf1) {
        const f16v st = __builtin_amdgcn_mfma_f32_32x32x16_bf16(kf, isB ? qfB : qfA,
                                                                z16, 0, 0, 0);
        float p[16];
#pragma unroll
        for (int r = 0; r < 16; ++r) p[r] = __builtin_amdgcn_exp2f(st[r]);
        if (t == nt - 1) {                      // diagonal tile: zero k > q
#pragma unroll
            for (int r = 0; r < 16; ++r) {
                const int kr = (r & 3) + 8 * (r >> 2) + 4 * hi;
                if (kr > l31) p[r] = 0.f;
            }
        }
        s8v pb[2];
#pragma unroll
        for (int half = 0; half < 2; ++half) {
            unsigned x0, x1, y0, y1;
            asm("v_cvt_pk_bf16_f32 %0, %1, %2" : "=v"(x0) : "v"(p[8*half+0]), "v"(p[8*half+1]));
            asm("v_cvt_pk_bf16_f32 %0, %1, %2" : "=v"(x1) : "v"(p[8*half+2]), "v"(p[8*half+3]));
            asm("v_cvt_pk_bf16_f32 %0, %1, %2" : "=v"(y0) : "v"(p[8*half+4]), "v"(p[8*half+5]));
            asm("v_cvt_pk_bf16_f32 %0, %1, %2" : "=v"(y1) : "v"(p[8*half+6]), "v"(p[8*half+7]));
            auto r0 = __builtin_amdgcn_permlane32_swap(x0, y0, false, false);
            auto r1 = __builtin_amdgcn_permlane32_swap(x1, y1, false, false);
            union { unsigned u[4]; s8v v; } bu;
            bu.u[0] = r0[0]; bu.u[1] = r1[0]; bu.u[2] = r0[1]; bu.u[3] = r1[1];
            pb[half] = bu.v;
        }
        if (isB) {
            aB0 = __builtin_amdgcn_mfma_f32_32x32x16_bf16(vf0, pb[0], aB0, 0, 0, 0);
            aB1 = __builtin_amdgcn_mfma_f32_32x32x16_bf16(vf1, pb[1], aB1, 0, 0, 0);
        } else {
            aA0 = __builtin_amdgcn_mfma_f32_32x32x16_bf16(vf0, pb[0], aA0, 0, 0, 0);
            aA1 = __builtin_amdgcn_mfma_f32_32x32x16_bf16(vf1, pb[1], aA1, 0, 0, 0);
        }
    };

    auto tile = [&](int t) {
        const s8v kf = *(const s8v*)(kp + t * 512 + hi * 256 + l31 * 8);
        s8v vf0 = vinit, vf1 = vinit;
        if (l31 < 16) {
            vf0 = *(const s8v*)(vp + t * 512 + hi * 128 + l31 * 8);
            vf1 = *(const s8v*)(vp + t * 512 + 256 + hi * 128 + l31 * 8);
        }
        stream_step(true, t, ntB, kf, vf0, vf1);         // stream B: every tile
        if (t < ntA)                                     // stream A: shared K/V
            stream_step(false, t, ntA, kf, vf0, vf1);
    };

    for (int t0 = 2 * wv; t0 < ntB; t0 += 8) {    // two tiles/iteration for ILP
        tile(t0);
        if (t0 + 1 < ntB) tile(t0 + 1);
    }

#pragma unroll
    for (int j = 0; j < 8; ++j) {
        ol[0][wv][j][lane] = aB0[j] + aB1[j];
        ol[1][wv][j][lane] = aA0[j] + aA1[j];
    }
    if (hi == 0) {
        ll[0][wv][l31] = aB0[8] + aB1[8];
        ll[1][wv][l31] = aA0[8] + aA1[8];
    }
    __syncthreads();

    if (wv < 2) {                               // wave 0 -> stream B, wave 1 -> stream A
        const int ss = wv;
        const int qw = (ss ? qbA : qbB) * 32;
        float l = (ll[ss][0][l31] + ll[ss][1][l31]) + (ll[ss][2][l31] + ll[ss][3][l31]);
        const float inv = __builtin_amdgcn_rcpf(l);
        float o[8];
#pragma unroll
        for (int j = 0; j < 8; ++j)
            o[j] = ((ol[ss][0][j][lane] + ol[ss][1][j][lane]) +
                    (ol[ss][2][j][lane] + ol[ss][3][j][lane])) * inv;
        const int b = bh >> 4, h = bh & 15;
        f4v o0, o1;
#pragma unroll
        for (int j = 0; j < 4; ++j) { o0[j] = o[j]; o1[j] = o[4 + j]; }
        float* op = out + ((size_t)b * S_LEN + qw + l31) * (NHEAD * HDIM) + h * HDIM;
        *(f4v*)(op + 4 * hi) = o0;        // d = 4*hi + 0..3
        *(f4v*)(op + 8 + 4 * hi) = o1;    // d = 8 + 4*hi + 0..3
    }
}

extern "C" void kernel_launch(void* const* d_in, const int* in_sizes, int n_in,
                              void* d_out, int out_size, void* d_ws, size_t ws_size,
                              hipStream_t stream)
{
    const float* Q  = (const float*)d_in[0];
    const float* K  = (const float*)d_in[1];
    const float* V  = (const float*)d_in[2];
    const float* WQ = (const float*)d_in[3];
    const float* WK = (const float*)d_in[4];
    const float* WV = (const float*)d_in[5];
    float* out = (float*)d_out;

    const size_t mat = (size_t)2 * NHEAD * S_LEN * HDIM;   // 2 MB bf16 each
    ushort* qh = (ushort*)d_ws;
    ushort* kh = qh + mat;
    ushort* vt = kh + mat;

    proj_kernel<<<dim3(64, 3), 1024, 0, stream>>>(Q, K, V, WQ, WK, WV, qh, kh, vt);
    attn_kernel<<<dim3(1024), 256, 0, stream>>>(qh, kh, vt, out);
}